// Round 2
// baseline (1233.202 us; speedup 1.0000x reference)
//
#include <hip/hip_runtime.h>
#include <hip/hip_bf16.h>

typedef __attribute__((ext_vector_type(8))) short bh8;
typedef __attribute__((ext_vector_type(4))) float fx4;
typedef __attribute__((ext_vector_type(4))) int ix4;

#define MFMA_BF16(a,b,c) __builtin_amdgcn_mfma_f32_16x16x32_bf16((a),(b),(c),0,0,0)

__device__ __forceinline__ unsigned short f2bf(float f){
  union { float f; unsigned u; } x; x.f = f;
  return (unsigned short)((x.u + 0x7fffu + ((x.u >> 16) & 1u)) >> 16);
}

__device__ __forceinline__ void gl_lds16(const void* g, void* l){
  typedef const void __attribute__((address_space(1)))* gp_t;
  typedef void __attribute__((address_space(3)))* lp_t;
  __builtin_amdgcn_global_load_lds((gp_t)g, (lp_t)l, 16, 0, 0);
}

// ---------------- f32 -> bf16 (RNE), 4 elems/thread ----------------
__global__ __launch_bounds__(256) void cvt_kernel(const float* __restrict__ in,
                                                  unsigned short* __restrict__ out, int n){
  int i = (blockIdx.x * 256 + threadIdx.x) * 4;
  if (i >= n) return;
  float4 v = *reinterpret_cast<const float4*>(in + i);
  ushort4 o;
  o.x = f2bf(v.x); o.y = f2bf(v.y); o.z = f2bf(v.z); o.w = f2bf(v.w);
  *reinterpret_cast<ushort4*>(out + i) = o;
}

// ---------------- NT GEMM: C[M][N] = A[M][K] * B[N][K]^T ----------------
// m97 structure: 128x128 tile, BK=32, 4 waves (each 64x64 = 4x4 frags of 16x16x32)
__global__ __launch_bounds__(256) void gemm_nt(const unsigned short* __restrict__ A,
                                               const unsigned short* __restrict__ B,
                                               void* __restrict__ Cout,
                                               int M, int N, int K, int out_f32){
  __shared__ __attribute__((aligned(16))) unsigned short As[128*32];
  __shared__ __attribute__((aligned(16))) unsigned short Bs[128*32];
  const int tid = threadIdx.x, lane = tid & 63, w = tid >> 6;
  const int row0 = blockIdx.x * 128, col0 = blockIdx.y * 128;
  const int wr = w >> 1, wc = w & 1;
  fx4 acc[4][4];
#pragma unroll
  for (int m=0;m<4;m++)
#pragma unroll
    for (int n=0;n<4;n++) acc[m][n] = (fx4){0.f,0.f,0.f,0.f};

  const int ldr = lane & 15;          // fragment row within 16
  const int kb  = (lane >> 4) * 16;   // fragment k byte offset (8 bf16)

  for (int k0 = 0; k0 < K; k0 += 32){
    __syncthreads();
#pragma unroll
    for (int i=0;i<2;i++){
      int chunk = w*2 + i;                 // 0..7, 1024B each
      int r  = chunk*16 + (lane >> 2);     // tile row
      int cb = (lane & 3) * 16;            // byte col within 64B row
      gl_lds16((const char*)A + ((size_t)(row0 + r)*K + k0)*2 + cb, (char*)As + chunk*1024);
      gl_lds16((const char*)B + ((size_t)(col0 + r)*K + k0)*2 + cb, (char*)Bs + chunk*1024);
    }
    __syncthreads();
    bh8 af[4], bf[4];
#pragma unroll
    for (int m=0;m<4;m++)
      af[m] = *reinterpret_cast<const bh8*>((const char*)As + (wr*64 + m*16 + ldr)*64 + kb);
#pragma unroll
    for (int n=0;n<4;n++)
      bf[n] = *reinterpret_cast<const bh8*>((const char*)Bs + (wc*64 + n*16 + ldr)*64 + kb);
#pragma unroll
    for (int m=0;m<4;m++)
#pragma unroll
      for (int n=0;n<4;n++)
        acc[m][n] = MFMA_BF16(af[m], bf[n], acc[m][n]);
  }
  const int er = (lane >> 4) * 4;
  const int ec = lane & 15;
  if (out_f32){
    float* C = (float*)Cout;
#pragma unroll
    for (int m=0;m<4;m++)
#pragma unroll
      for (int n=0;n<4;n++)
#pragma unroll
        for (int j=0;j<4;j++)
          C[(size_t)(row0 + wr*64 + m*16 + er + j)*N + (col0 + wc*64 + n*16 + ec)] = acc[m][n][j];
  } else {
    unsigned short* C = (unsigned short*)Cout;
#pragma unroll
    for (int m=0;m<4;m++)
#pragma unroll
      for (int n=0;n<4;n++)
#pragma unroll
        for (int j=0;j<4;j++)
          C[(size_t)(row0 + wr*64 + m*16 + er + j)*N + (col0 + wc*64 + n*16 + ec)] = f2bf(acc[m][n][j]);
  }
}

// ---------------- causal GQA flash attention ----------------
// block = 4 waves, wave owns 16 q rows; KV tile = 32; D = 128
#define VS 40   // V^T LDS row stride (elems)
#define PSS 40  // P LDS row stride (elems)
__global__ __launch_bounds__(256) void attn_kernel(const unsigned short* __restrict__ Q,
                                                   const unsigned short* __restrict__ Km,
                                                   const unsigned short* __restrict__ Vm,
                                                   unsigned short* __restrict__ O){
  __shared__ __attribute__((aligned(16))) unsigned short Ks[32*128];   // xor-swizzled rows
  __shared__ __attribute__((aligned(16))) unsigned short Vt[128*VS];   // V^T [d][kv]
  __shared__ __attribute__((aligned(16))) unsigned short Ps[4][16*PSS];// per-wave P [q][kv]
  const int tid = threadIdx.x, lane = tid & 63, w = tid >> 6;
  const int bq = (int)gridDim.x - 1 - (int)blockIdx.x;  // heavy blocks first
  const int head = blockIdx.y;
  const int b = head >> 5, h = head & 31, kvh = h >> 2;
  const int qrow0 = bq*64 + w*16;
  const size_t tokbase = (size_t)b * 2048;

  bh8 qf[4];
  {
    const char* qp = (const char*)Q + ((tokbase + qrow0 + (lane & 15))*4096 + h*128)*2;
#pragma unroll
    for (int kk=0;kk<4;kk++)
      qf[kk] = *reinterpret_cast<const bh8*>(qp + kk*64 + (lane>>4)*16);
  }
  float mrow[4], lrow[4];
  fx4 acc[8];
#pragma unroll
  for (int j=0;j<4;j++){ mrow[j] = -1e30f; lrow[j] = 0.f; }
#pragma unroll
  for (int f=0;f<8;f++) acc[f] = (fx4){0.f,0.f,0.f,0.f};

  const int ntile = 2*bq + 2;
  for (int kt = 0; kt < ntile; ++kt){
    const int kv0 = kt*32;
    __syncthreads();
    { // stage K tile: 32 rows x 256B = 8192B; 2 x 16B per thread, G4 xor swizzle
#pragma unroll
      for (int i=0;i<2;i++){
        int idx = i*256 + tid;
        int r = idx >> 4, cb = (idx & 15)*16;    // row 0..31, byte col 0..240
        ix4 kv = *reinterpret_cast<const ix4*>((const char*)Km + ((tokbase + kv0 + r)*1024 + kvh*128)*2 + cb);
        *reinterpret_cast<ix4*>((char*)Ks + r*256 + (cb ^ ((r & 7) << 4))) = kv;
      }
    }
    { // stage V^T: thread owns d = tid&127, kv-half kh; packed b128 writes
      int d = tid & 127, kh = tid >> 7;
      const unsigned short* vsrc = Vm + (tokbase + kv0 + kh*16)*1024 + kvh*128 + d;
      unsigned short vv[16];
#pragma unroll
      for (int e=0;e<16;e++) vv[e] = vsrc[(size_t)e*1024];
      ix4 p0, p1;
#pragma unroll
      for (int e=0;e<4;e++) p0[e] = (int)vv[2*e]   | ((int)vv[2*e+1] << 16);
#pragma unroll
      for (int e=0;e<4;e++) p1[e] = (int)vv[8+2*e] | ((int)vv[9+2*e] << 16);
      *reinterpret_cast<ix4*>((char*)Vt + d*(VS*2) + kh*32)      = p0;
      *reinterpret_cast<ix4*>((char*)Vt + d*(VS*2) + kh*32 + 16) = p1;
    }
    __syncthreads();
    if (kv0 <= qrow0 + 15){
      fx4 s0 = (fx4){0.f,0.f,0.f,0.f}, s1 = s0;
#pragma unroll
      for (int kk=0;kk<4;kk++){
        int r0 = lane & 15, r1 = 16 + (lane & 15);
        int ob = kk*64 + (lane>>4)*16;
        bh8 k0f = *reinterpret_cast<const bh8*>((const char*)Ks + r0*256 + (ob ^ ((r0 & 7)<<4)));
        bh8 k1f = *reinterpret_cast<const bh8*>((const char*)Ks + r1*256 + (ob ^ ((r1 & 7)<<4)));
        s0 = MFMA_BF16(qf[kk], k0f, s0);
        s1 = MFMA_BF16(qf[kk], k1f, s1);
      }
      const float scale = 0.08838834764831845f;
      float scl[4], p0v[4], p1v[4];
#pragma unroll
      for (int j=0;j<4;j++){
        int q = qrow0 + ((lane>>4)<<2) + j;
        float v0 = s0[j]*scale; if (kv0 + (lane & 15) > q)      v0 = -1e30f;
        float v1 = s1[j]*scale; if (kv0 + 16 + (lane & 15) > q) v1 = -1e30f;
        float mx = fmaxf(v0, v1);
        mx = fmaxf(mx, __shfl_xor(mx, 1));
        mx = fmaxf(mx, __shfl_xor(mx, 2));
        mx = fmaxf(mx, __shfl_xor(mx, 4));
        mx = fmaxf(mx, __shfl_xor(mx, 8));
        float mnew = fmaxf(mrow[j], mx);
        float sc = __expf(mrow[j] - mnew);
        mrow[j] = mnew;
        float p0 = __expf(v0 - mnew), p1 = __expf(v1 - mnew);
        float rs = p0 + p1;
        rs += __shfl_xor(rs, 1);
        rs += __shfl_xor(rs, 2);
        rs += __shfl_xor(rs, 4);
        rs += __shfl_xor(rs, 8);
        lrow[j] = lrow[j]*sc + rs;
        scl[j] = sc; p0v[j] = p0; p1v[j] = p1;
      }
#pragma unroll
      for (int f=0;f<8;f++)
#pragma unroll
        for (int j=0;j<4;j++) acc[f][j] *= scl[j];
      // transpose P through per-wave LDS (pad stride breaks conflicts)
      unsigned short* pw = &Ps[w][0];
#pragma unroll
      for (int j=0;j<4;j++){
        int q = ((lane>>4)<<2) + j;
        pw[q*PSS +      (lane & 15)] = f2bf(p0v[j]);
        pw[q*PSS + 16 + (lane & 15)] = f2bf(p1v[j]);
      }
      asm volatile("s_waitcnt lgkmcnt(0)" ::: "memory");
      bh8 pa = *reinterpret_cast<const bh8*>((const char*)pw + (lane & 15)*(PSS*2) + (lane>>4)*16);
#pragma unroll
      for (int f=0;f<8;f++){
        bh8 vb = *reinterpret_cast<const bh8*>((const char*)Vt + (f*16 + (lane & 15))*(VS*2) + (lane>>4)*16);
        acc[f] = MFMA_BF16(pa, vb, acc[f]);
      }
    }
  }
#pragma unroll
  for (int f=0;f<8;f++)
#pragma unroll
    for (int j=0;j<4;j++){
      int q = qrow0 + ((lane>>4)<<2) + j;
      float o = acc[f][j] / lrow[j];
      O[(tokbase + q)*4096 + h*128 + f*16 + (lane & 15)] = f2bf(o);
    }
}

extern "C" void kernel_launch(void* const* d_in, const int* in_sizes, int n_in,
                              void* d_out, int out_size, void* d_ws, size_t ws_size,
                              hipStream_t stream){
  const float* x  = (const float*)d_in[0];
  const float* Wq = (const float*)d_in[1];
  const float* Wk = (const float*)d_in[2];
  const float* Wv = (const float*)d_in[3];
  const float* Wo = (const float*)d_in[4];
  char* ws = (char*)d_ws;
  const size_t MB = (size_t)1 << 20;
  unsigned short* xb  = (unsigned short*)(ws);             // 32 MiB (reused as attn-out)
  unsigned short* Wqb = (unsigned short*)(ws + 32*MB);     // 32 MiB (reused for Wo)
  unsigned short* Wkb = (unsigned short*)(ws + 64*MB);     // 8 MiB
  unsigned short* Wvb = (unsigned short*)(ws + 72*MB);     // 8 MiB
  unsigned short* Qb  = (unsigned short*)(ws + 80*MB);     // 32 MiB
  unsigned short* Kb  = (unsigned short*)(ws + 112*MB);    // 8 MiB
  unsigned short* Vb  = (unsigned short*)(ws + 120*MB);    // 8 MiB  (total 128 MiB)

  const int NT = 2*2048;
  auto cvt = [&](const float* in, unsigned short* out, int n){
    cvt_kernel<<<dim3(n/1024), 256, 0, stream>>>(in, out, n);
  };
  cvt(x,  xb,  NT*4096);
  cvt(Wq, Wqb, 4096*4096);
  cvt(Wk, Wkb, 1024*4096);
  cvt(Wv, Wvb, 1024*4096);
  gemm_nt<<<dim3(32,32), 256, 0, stream>>>(xb, Wqb, Qb, NT, 4096, 4096, 0);
  gemm_nt<<<dim3(32, 8), 256, 0, stream>>>(xb, Wkb, Kb, NT, 1024, 4096, 0);
  gemm_nt<<<dim3(32, 8), 256, 0, stream>>>(xb, Wvb, Vb, NT, 1024, 4096, 0);
  cvt(Wo, Wqb, 4096*4096);                         // Wq slot now dead -> Wo
  attn_kernel<<<dim3(32,64), 256, 0, stream>>>(Qb, Kb, Vb, xb);  // x slot now dead -> attn out
  gemm_nt<<<dim3(32,32), 256, 0, stream>>>(xb, Wqb, d_out, NT, 4096, 4096, 1);
}